// Round 3
// baseline (160.612 us; speedup 1.0000x reference)
//
#include <hip/hip_runtime.h>
#include <math.h>

#define BB 32
#define SS 2048
#define DD 512
#define ECHUNKS 4    // e-dimension split for compute_u parallelism
#define SBLOCKS 64   // blocks per batch in the scores kernel

// ---------------------------------------------------------------------------
// K1: partial u. part[k][b][d] = sum_{e in chunk k} hidden[b,e] * W[e,d]
// Bias dropped: it adds a per-batch constant to every logit -> softmax-invariant.
// Also zeroes the per-batch finisher counters (visible to K2 via kernel boundary).
// grid = (ECHUNKS, B), block = 256. Thread t owns d-pair (2t, 2t+1).
// ---------------------------------------------------------------------------
__global__ void __launch_bounds__(256) compute_u_partial(
    const float* __restrict__ hidden, const float* __restrict__ W,
    float* __restrict__ part, int* __restrict__ counters) {
    const int k = blockIdx.x;
    const int b = blockIdx.y;

    if (k == 0 && threadIdx.x == 0) counters[b] = 0;

    __shared__ float h_s[DD / ECHUNKS];            // 128 floats
    if (threadIdx.x < DD / ECHUNKS)
        h_s[threadIdx.x] = hidden[b * DD + k * (DD / ECHUNKS) + threadIdx.x];
    __syncthreads();

    const int t = threadIdx.x;
    float acc0 = 0.f, acc1 = 0.f;
    const float2* W2 = (const float2*)W;
    #pragma unroll 8
    for (int i = 0; i < DD / ECHUNKS; ++i) {
        const int e = k * (DD / ECHUNKS) + i;
        const float he = h_s[i];
        const float2 w = W2[(size_t)e * (DD / 2) + t];   // 2 KB coalesced / iter
        acc0 = fmaf(he, w.x, acc0);
        acc1 = fmaf(he, w.y, acc1);
    }
    ((float2*)(part + (size_t)(k * BB + b) * DD))[t] = make_float2(acc0, acc1);
}

// ---------------------------------------------------------------------------
// K2: logits[b,s] = dot(enc[b,s,:], u[b,:]); last block per batch also does
// the softmax in place (split-k finisher pattern: threadfence + agent-scope
// atomic counter -- no spinning, no dispatch-order assumption).
// grid = (SBLOCKS, B), block = 256 (4 waves). Lane l holds u[b,8l..8l+7].
// ---------------------------------------------------------------------------
__global__ void __launch_bounds__(256) scores_softmax_kernel(
    const float* __restrict__ enc, const float* __restrict__ part,
    float* __restrict__ logits, int* __restrict__ counters) {
    const int b    = blockIdx.y;
    const int lane = threadIdx.x & 63;
    const int wv   = threadIdx.x >> 6;

    // Gather this lane's u fragment from the ECHUNKS partials (L2-hot).
    float4 u0 = make_float4(0.f, 0.f, 0.f, 0.f);
    float4 u1 = make_float4(0.f, 0.f, 0.f, 0.f);
    #pragma unroll
    for (int k = 0; k < ECHUNKS; ++k) {
        const float4* pk = (const float4*)(part + (size_t)(k * BB + b) * DD);
        const float4 a = pk[lane * 2 + 0];
        const float4 c = pk[lane * 2 + 1];
        u0.x += a.x; u0.y += a.y; u0.z += a.z; u0.w += a.w;
        u1.x += c.x; u1.y += c.y; u1.z += c.z; u1.w += c.w;
    }

    const int waves_per_b = SBLOCKS * 4;
    const int wave_id     = blockIdx.x * 4 + wv;
    const float4* encb = (const float4*)(enc + (size_t)b * SS * DD);

    #pragma unroll 2
    for (int s = wave_id; s < SS; s += waves_per_b) {   // 8 iterations
        const float4* row = encb + (size_t)s * (DD / 4);
        float4 e0 = row[lane * 2 + 0];   // 64 lanes x 32 B = full 2 KB row
        float4 e1 = row[lane * 2 + 1];
        float acc = e0.x * u0.x + e0.y * u0.y + e0.z * u0.z + e0.w * u0.w
                  + e1.x * u1.x + e1.y * u1.y + e1.z * u1.z + e1.w * u1.w;
        #pragma unroll
        for (int off = 32; off > 0; off >>= 1)
            acc += __shfl_xor(acc, off, 64);
        if (lane == 0) logits[b * SS + s] = acc;
    }

    // ---- finisher election -------------------------------------------------
    __shared__ int is_last;
    __shared__ float red_m[4];
    __shared__ float red_s[4];
    __syncthreads();                       // drains all stores (vmcnt(0) before barrier)
    if (threadIdx.x == 0) {
        __threadfence();                   // agent-scope: flush logits past per-XCD L2
        int done = __hip_atomic_fetch_add(&counters[b], 1,
                                          __ATOMIC_ACQ_REL, __HIP_MEMORY_SCOPE_AGENT);
        is_last = (done == SBLOCKS - 1);
    }
    __syncthreads();
    if (!is_last) return;

    // ---- softmax over logits[b, 0..2048) in place --------------------------
    const int t = threadIdx.x;
    float4* p = (float4*)(logits + b * SS);        // 512 float4s, 256 threads x 2
    float4 v0 = p[t];
    float4 v1 = p[t + 256];

    float m = fmaxf(fmaxf(fmaxf(v0.x, v0.y), fmaxf(v0.z, v0.w)),
                    fmaxf(fmaxf(v1.x, v1.y), fmaxf(v1.z, v1.w)));
    #pragma unroll
    for (int off = 32; off > 0; off >>= 1)
        m = fmaxf(m, __shfl_xor(m, off, 64));
    if (lane == 0) red_m[wv] = m;
    __syncthreads();
    m = fmaxf(fmaxf(red_m[0], red_m[1]), fmaxf(red_m[2], red_m[3]));

    v0.x = __expf(v0.x - m); v0.y = __expf(v0.y - m);
    v0.z = __expf(v0.z - m); v0.w = __expf(v0.w - m);
    v1.x = __expf(v1.x - m); v1.y = __expf(v1.y - m);
    v1.z = __expf(v1.z - m); v1.w = __expf(v1.w - m);

    float sum = v0.x + v0.y + v0.z + v0.w + v1.x + v1.y + v1.z + v1.w;
    #pragma unroll
    for (int off = 32; off > 0; off >>= 1)
        sum += __shfl_xor(sum, off, 64);
    if (lane == 0) red_s[wv] = sum;
    __syncthreads();
    sum = red_s[0] + red_s[1] + red_s[2] + red_s[3];

    const float inv = 1.f / sum;
    v0.x *= inv; v0.y *= inv; v0.z *= inv; v0.w *= inv;
    v1.x *= inv; v1.y *= inv; v1.z *= inv; v1.w *= inv;
    p[t]       = v0;
    p[t + 256] = v1;
}

extern "C" void kernel_launch(void* const* d_in, const int* in_sizes, int n_in,
                              void* d_out, int out_size, void* d_ws, size_t ws_size,
                              hipStream_t stream) {
    const float* hidden = (const float*)d_in[0];   // [B,1,D]
    const float* enc    = (const float*)d_in[1];   // [B,S,D]
    const float* W      = (const float*)d_in[2];   // [D,D] (W[e,d])
    // d_in[3] = bias: per-batch constant on all logits -> softmax-invariant, unused.
    float* out  = (float*)d_out;                   // [B,1,S] fp32
    float* part = (float*)d_ws;                    // ECHUNKS*B*D floats = 256 KB
    int* counters = (int*)((char*)d_ws + (size_t)ECHUNKS * BB * DD * sizeof(float));

    compute_u_partial<<<dim3(ECHUNKS, BB), dim3(256), 0, stream>>>(hidden, W, part, counters);
    scores_softmax_kernel<<<dim3(SBLOCKS, BB), dim3(256), 0, stream>>>(enc, part, out, counters);
}

// Round 4
// 34.559 us; speedup vs baseline: 4.6475x; 4.6475x over previous
//
#include <hip/hip_runtime.h>
#include <math.h>

#define BB 32
#define SS 2048
#define DD 512
#define ECHUNKS 8    // e-dimension split for compute_u parallelism
#define SBLOCKS 64   // blocks per batch in the scores kernel

// ---------------------------------------------------------------------------
// K1: partial u. part[k][b][d] = sum_{e in chunk k} hidden[b,e] * W[e,d]
// Bias dropped: adds a per-batch constant to every logit -> softmax-invariant.
// grid = (ECHUNKS, B), block = 256. Thread t owns d-pair (2t, 2t+1).
// ---------------------------------------------------------------------------
__global__ void __launch_bounds__(256) compute_u_partial(
    const float* __restrict__ hidden, const float* __restrict__ W,
    float* __restrict__ part) {
    const int k = blockIdx.x;
    const int b = blockIdx.y;
    __shared__ float h_s[DD / ECHUNKS];            // 64 floats
    if (threadIdx.x < DD / ECHUNKS)
        h_s[threadIdx.x] = hidden[b * DD + k * (DD / ECHUNKS) + threadIdx.x];
    __syncthreads();

    const int t = threadIdx.x;
    float acc0 = 0.f, acc1 = 0.f;
    const float2* W2 = (const float2*)W;
    #pragma unroll 8
    for (int i = 0; i < DD / ECHUNKS; ++i) {
        const int e = k * (DD / ECHUNKS) + i;
        const float he = h_s[i];
        const float2 w = W2[(size_t)e * (DD / 2) + t];   // 2 KB coalesced / iter
        acc0 = fmaf(he, w.x, acc0);
        acc1 = fmaf(he, w.y, acc1);
    }
    ((float2*)(part + (size_t)(k * BB + b) * DD))[t] = make_float2(acc0, acc1);
}

// ---------------------------------------------------------------------------
// K2: logits[b,s] = dot(enc[b,s,:], u[b,:]) with u summed from partials.
// grid = (SBLOCKS, B), block = 256 (4 waves). Lane l holds u[b,8l..8l+7].
// Rows processed in PAIRS: both rows' loads issue together (4 KB in flight
// per wave) and the two shuffle-reduce chains interleave (independent ILP).
// NO in-kernel cross-block sync: the R3 fused finisher's 2048 agent-scope
// fences caused L2 writeback storms (232us @ 3.7% BW). Launch boundary is
// the cheap coherence point.
// ---------------------------------------------------------------------------
__global__ void __launch_bounds__(256) scores_kernel(
    const float* __restrict__ enc, const float* __restrict__ part,
    float* __restrict__ logits) {
    const int b    = blockIdx.y;
    const int lane = threadIdx.x & 63;
    const int wv   = threadIdx.x >> 6;

    // Gather this lane's u fragment from the ECHUNKS partials (L2-hot).
    float4 u0 = make_float4(0.f, 0.f, 0.f, 0.f);
    float4 u1 = make_float4(0.f, 0.f, 0.f, 0.f);
    #pragma unroll
    for (int k = 0; k < ECHUNKS; ++k) {
        const float4* pk = (const float4*)(part + (size_t)(k * BB + b) * DD);
        const float4 a = pk[lane * 2 + 0];
        const float4 c = pk[lane * 2 + 1];
        u0.x += a.x; u0.y += a.y; u0.z += a.z; u0.w += a.w;
        u1.x += c.x; u1.y += c.y; u1.z += c.z; u1.w += c.w;
    }

    const int waves_per_b = SBLOCKS * 4;
    const int wave_id     = blockIdx.x * 4 + wv;
    const float4* encb = (const float4*)(enc + (size_t)b * SS * DD);

    // 8 rows per wave -> 4 paired iterations.
    #pragma unroll 2
    for (int k = 0; k < SS / (SBLOCKS * 4); k += 2) {
        const int s0 = wave_id + k * waves_per_b;
        const int s1 = s0 + waves_per_b;
        const float4* r0 = encb + (size_t)s0 * (DD / 4);
        const float4* r1 = encb + (size_t)s1 * (DD / 4);
        float4 a0 = r0[lane * 2 + 0];
        float4 a1 = r0[lane * 2 + 1];
        float4 c0 = r1[lane * 2 + 0];
        float4 c1 = r1[lane * 2 + 1];
        float acc0 = a0.x * u0.x + a0.y * u0.y + a0.z * u0.z + a0.w * u0.w
                   + a1.x * u1.x + a1.y * u1.y + a1.z * u1.z + a1.w * u1.w;
        float acc1 = c0.x * u0.x + c0.y * u0.y + c0.z * u0.z + c0.w * u0.w
                   + c1.x * u1.x + c1.y * u1.y + c1.z * u1.z + c1.w * u1.w;
        #pragma unroll
        for (int off = 32; off > 0; off >>= 1) {
            acc0 += __shfl_xor(acc0, off, 64);
            acc1 += __shfl_xor(acc1, off, 64);
        }
        if (lane == 0) {
            logits[b * SS + s0] = acc0;
            logits[b * SS + s1] = acc1;
        }
    }
}

// ---------------------------------------------------------------------------
// K3: in-place softmax over S per batch. One block (512 thr, 8 waves),
// float4 per thread: 512*4 = 2048 = SS.
// ---------------------------------------------------------------------------
__global__ void __launch_bounds__(512) softmax_kernel(float* __restrict__ io) {
    const int b = blockIdx.x;
    const int t = threadIdx.x;
    const int lane = t & 63, wv = t >> 6;
    float4* p = (float4*)(io + b * SS);

    float4 v = p[t];
    float m = fmaxf(fmaxf(v.x, v.y), fmaxf(v.z, v.w));
    #pragma unroll
    for (int off = 32; off > 0; off >>= 1)
        m = fmaxf(m, __shfl_xor(m, off, 64));

    __shared__ float red_m[8];
    __shared__ float red_s[8];
    if (lane == 0) red_m[wv] = m;
    __syncthreads();
    m = red_m[0];
    #pragma unroll
    for (int i = 1; i < 8; ++i) m = fmaxf(m, red_m[i]);

    v.x = __expf(v.x - m);
    v.y = __expf(v.y - m);
    v.z = __expf(v.z - m);
    v.w = __expf(v.w - m);
    float sum = v.x + v.y + v.z + v.w;
    #pragma unroll
    for (int off = 32; off > 0; off >>= 1)
        sum += __shfl_xor(sum, off, 64);
    if (lane == 0) red_s[wv] = sum;
    __syncthreads();
    sum = 0.f;
    #pragma unroll
    for (int i = 0; i < 8; ++i) sum += red_s[i];

    const float inv = 1.f / sum;
    v.x *= inv; v.y *= inv; v.z *= inv; v.w *= inv;
    p[t] = v;
}

extern "C" void kernel_launch(void* const* d_in, const int* in_sizes, int n_in,
                              void* d_out, int out_size, void* d_ws, size_t ws_size,
                              hipStream_t stream) {
    const float* hidden = (const float*)d_in[0];   // [B,1,D]
    const float* enc    = (const float*)d_in[1];   // [B,S,D]
    const float* W      = (const float*)d_in[2];   // [D,D] (W[e,d])
    // d_in[3] = bias: per-batch constant on all logits -> softmax-invariant, unused.
    float* out  = (float*)d_out;                   // [B,1,S] fp32
    float* part = (float*)d_ws;                    // ECHUNKS*B*D floats = 512 KB

    compute_u_partial<<<dim3(ECHUNKS, BB), dim3(256), 0, stream>>>(hidden, W, part);
    scores_kernel<<<dim3(SBLOCKS, BB), dim3(256), 0, stream>>>(enc, part, out);
    softmax_kernel<<<dim3(BB), dim3(512), 0, stream>>>(out);
}

// Round 5
// 33.830 us; speedup vs baseline: 4.7476x; 1.0215x over previous
//
#include <hip/hip_runtime.h>
#include <math.h>

#define BB 32
#define SS 2048
#define DD 512
#define ECHUNKS 8    // e-dimension split for compute_u parallelism
#define SBLOCKS 64   // blocks per batch in the scores kernel

// ---------------------------------------------------------------------------
// K1: partial u. part[k][b][d] = sum_{e in chunk k} hidden[b,e] * W[e,d]
// Bias dropped: adds a per-batch constant to every logit -> softmax-invariant.
// grid = (ECHUNKS, B), block = 256. Thread t owns d-pair (2t, 2t+1).
// ---------------------------------------------------------------------------
__global__ void __launch_bounds__(256) compute_u_partial(
    const float* __restrict__ hidden, const float* __restrict__ W,
    float* __restrict__ part) {
    const int k = blockIdx.x;
    const int b = blockIdx.y;
    __shared__ float h_s[DD / ECHUNKS];            // 64 floats
    if (threadIdx.x < DD / ECHUNKS)
        h_s[threadIdx.x] = hidden[b * DD + k * (DD / ECHUNKS) + threadIdx.x];
    __syncthreads();

    const int t = threadIdx.x;
    float acc0 = 0.f, acc1 = 0.f;
    const float2* W2 = (const float2*)W;
    #pragma unroll 8
    for (int i = 0; i < DD / ECHUNKS; ++i) {
        const int e = k * (DD / ECHUNKS) + i;
        const float he = h_s[i];
        const float2 w = W2[(size_t)e * (DD / 2) + t];   // 2 KB coalesced / iter
        acc0 = fmaf(he, w.x, acc0);
        acc1 = fmaf(he, w.y, acc1);
    }
    ((float2*)(part + (size_t)(k * BB + b) * DD))[t] = make_float2(acc0, acc1);
}

// ---------------------------------------------------------------------------
// K2: logits[b,s] = dot(enc[b,s,:], u[b,:]) with u summed from partials.
// grid = (SBLOCKS, B), block = 256 (4 waves). Lane l holds u[b,8l..8l+7].
// Epilogue: block-local softmax partial (max, sum-exp) over its 32 rows ->
// 8 B to ws. No cross-block sync (R3 lesson: 2048 agent-scope fences = 232us
// @ 3.7% BW; launch boundary is the cheap coherence point).
// ---------------------------------------------------------------------------
__global__ void __launch_bounds__(256) scores_kernel(
    const float* __restrict__ enc, const float* __restrict__ part,
    float* __restrict__ logits, float2* __restrict__ partials) {
    const int b    = blockIdx.y;
    const int lane = threadIdx.x & 63;
    const int wv   = threadIdx.x >> 6;

    // Gather this lane's u fragment from the ECHUNKS partials (L2/L3-hot).
    float4 u0 = make_float4(0.f, 0.f, 0.f, 0.f);
    float4 u1 = make_float4(0.f, 0.f, 0.f, 0.f);
    #pragma unroll
    for (int k = 0; k < ECHUNKS; ++k) {
        const float4* pk = (const float4*)(part + (size_t)(k * BB + b) * DD);
        const float4 a = pk[lane * 2 + 0];
        const float4 c = pk[lane * 2 + 1];
        u0.x += a.x; u0.y += a.y; u0.z += a.z; u0.w += a.w;
        u1.x += c.x; u1.y += c.y; u1.z += c.z; u1.w += c.w;
    }

    const int waves_per_b = SBLOCKS * 4;
    const int wave_id     = blockIdx.x * 4 + wv;
    const float4* encb = (const float4*)(enc + (size_t)b * SS * DD);

    float rv[8];                               // this wave's 8 row logits
    #pragma unroll
    for (int kk = 0; kk < 4; ++kk) {           // rows in pairs: ILP + 4KB in flight
        const int s0 = wave_id + (2 * kk) * waves_per_b;
        const int s1 = s0 + waves_per_b;
        const float4* r0 = encb + (size_t)s0 * (DD / 4);
        const float4* r1 = encb + (size_t)s1 * (DD / 4);
        float4 a0 = r0[lane * 2 + 0];
        float4 a1 = r0[lane * 2 + 1];
        float4 c0 = r1[lane * 2 + 0];
        float4 c1 = r1[lane * 2 + 1];
        float acc0 = a0.x * u0.x + a0.y * u0.y + a0.z * u0.z + a0.w * u0.w
                   + a1.x * u1.x + a1.y * u1.y + a1.z * u1.z + a1.w * u1.w;
        float acc1 = c0.x * u0.x + c0.y * u0.y + c0.z * u0.z + c0.w * u0.w
                   + c1.x * u1.x + c1.y * u1.y + c1.z * u1.z + c1.w * u1.w;
        #pragma unroll
        for (int off = 32; off > 0; off >>= 1) {
            acc0 += __shfl_xor(acc0, off, 64);
            acc1 += __shfl_xor(acc1, off, 64);
        }
        rv[2 * kk]     = acc0;                 // butterfly: all lanes hold sums
        rv[2 * kk + 1] = acc1;
        if (lane == 0) {
            logits[b * SS + s0] = acc0;
            logits[b * SS + s1] = acc1;
        }
    }

    // ---- per-block softmax partial: (max, sum exp) over 32 rows ------------
    float mw = rv[0];
    #pragma unroll
    for (int i = 1; i < 8; ++i) mw = fmaxf(mw, rv[i]);
    float sw = 0.f;
    #pragma unroll
    for (int i = 0; i < 8; ++i) sw += __expf(rv[i] - mw);

    __shared__ float2 wred[4];
    if (lane == 0) wred[wv] = make_float2(mw, sw);
    __syncthreads();
    if (threadIdx.x == 0) {
        float2 p0 = wred[0], p1 = wred[1], p2 = wred[2], p3 = wred[3];
        float mb = fmaxf(fmaxf(p0.x, p1.x), fmaxf(p2.x, p3.x));
        float sb = p0.y * __expf(p0.x - mb) + p1.y * __expf(p1.x - mb)
                 + p2.y * __expf(p2.x - mb) + p3.y * __expf(p3.x - mb);
        partials[b * SBLOCKS + blockIdx.x] = make_float2(mb, sb);
    }
}

// ---------------------------------------------------------------------------
// K3: normalize. grid = (2, B), block = 256; thread handles one float4.
// Every wave redundantly reduces the 64 (m,S) partials via shuffles (512 B,
// no LDS, no syncthreads), then applies exp(x-m)/S elementwise in place.
// ---------------------------------------------------------------------------
__global__ void __launch_bounds__(256) normalize_kernel(
    float* __restrict__ logits, const float2* __restrict__ partials) {
    const int b    = blockIdx.y;
    const int lane = threadIdx.x & 63;

    const float2 pl = partials[b * SBLOCKS + lane];
    float m = pl.x;
    #pragma unroll
    for (int off = 32; off > 0; off >>= 1)
        m = fmaxf(m, __shfl_xor(m, off, 64));
    float s = pl.y * __expf(pl.x - m);
    #pragma unroll
    for (int off = 32; off > 0; off >>= 1)
        s += __shfl_xor(s, off, 64);
    const float inv = 1.f / s;

    float4* p = (float4*)(logits + b * SS);
    const int idx = blockIdx.x * 256 + threadIdx.x;     // 512 float4s per batch
    float4 v = p[idx];
    v.x = __expf(v.x - m) * inv;
    v.y = __expf(v.y - m) * inv;
    v.z = __expf(v.z - m) * inv;
    v.w = __expf(v.w - m) * inv;
    p[idx] = v;
}

extern "C" void kernel_launch(void* const* d_in, const int* in_sizes, int n_in,
                              void* d_out, int out_size, void* d_ws, size_t ws_size,
                              hipStream_t stream) {
    const float* hidden = (const float*)d_in[0];   // [B,1,D]
    const float* enc    = (const float*)d_in[1];   // [B,S,D]
    const float* W      = (const float*)d_in[2];   // [D,D] (W[e,d])
    // d_in[3] = bias: per-batch constant on all logits -> softmax-invariant, unused.
    float* out  = (float*)d_out;                   // [B,1,S] fp32
    float* part = (float*)d_ws;                    // ECHUNKS*B*D floats = 512 KB
    float2* partials = (float2*)((char*)d_ws + (size_t)ECHUNKS * BB * DD * sizeof(float));

    compute_u_partial<<<dim3(ECHUNKS, BB), dim3(256), 0, stream>>>(hidden, W, part);
    scores_kernel<<<dim3(SBLOCKS, BB), dim3(256), 0, stream>>>(enc, part, out, partials);
    normalize_kernel<<<dim3(2, BB), dim3(256), 0, stream>>>(out, partials);
}

// Round 6
// 32.740 us; speedup vs baseline: 4.9057x; 1.0333x over previous
//
#include <hip/hip_runtime.h>
#include <math.h>

#define BB 32
#define SS 2048
#define DD 512
#define SBLOCKS 64   // blocks per batch in the scores kernel

// ---------------------------------------------------------------------------
// K1: u[b,d] = sum_e hidden[b,e] * W[e,d], fully reduced (no partials).
// Bias dropped: adds a per-batch constant to every logit -> softmax-invariant.
// Parallelism over d-chunks: grid = (8, B); block (dc,b) computes
// u[b, dc*64 .. dc*64+64). 256 threads = 8 e-groups x 32 float2 d-lanes;
// LDS-reduce the 8 e-group partials at the end.
// ---------------------------------------------------------------------------
__global__ void __launch_bounds__(256) compute_u_kernel(
    const float* __restrict__ hidden, const float* __restrict__ W,
    float* __restrict__ u) {
    const int dc = blockIdx.x;
    const int b  = blockIdx.y;
    const int t  = threadIdx.x;
    const int dp = t & 31;        // float2 index within the 64-wide d-chunk
    const int eg = t >> 5;        // e-group: e in [eg*64, eg*64+64)

    __shared__ float h_s[DD];
    #pragma unroll
    for (int i = 0; i < DD / 256; ++i)
        h_s[t + i * 256] = hidden[b * DD + t + i * 256];
    __syncthreads();

    const float2* W2 = (const float2*)W;     // W2[e*256 + d/2]
    const int base_j = dc * 32;
    float2 acc = make_float2(0.f, 0.f);
    #pragma unroll 8
    for (int i = 0; i < 64; ++i) {
        const int e = eg * 64 + i;
        const float he = h_s[e];
        const float2 w = W2[(size_t)e * (DD / 2) + base_j + dp];
        acc.x = fmaf(he, w.x, acc.x);
        acc.y = fmaf(he, w.y, acc.y);
    }

    __shared__ float2 red[8][32];
    red[eg][dp] = acc;
    __syncthreads();
    if (t < 32) {
        float2 s = make_float2(0.f, 0.f);
        #pragma unroll
        for (int g = 0; g < 8; ++g) {
            s.x += red[g][t].x;
            s.y += red[g][t].y;
        }
        ((float2*)(u + b * DD))[dc * 32 + t] = s;
    }
}

// ---------------------------------------------------------------------------
// K2: logits[b,s] = dot(enc[b,s,:], u[b,:]).
// grid = (SBLOCKS, B), block = 256 (4 waves). Lane l holds u[b,8l..8l+7]
// (2 float4 loads, L2-hot). CONTIGUOUS tiling: block x owns rows
// [x*32, x*32+32), wave w rows [x*32+8w, +8), processed as adjacent pairs ->
// 4 KB contiguous per pair, 16 KB stream per wave (DRAM row locality).
// Epilogue: per-block (max, sum-exp) partial -> 8 B. No cross-block sync
// (R3 lesson: 2048 agent-scope fences = 232us @ 3.7% BW).
// ---------------------------------------------------------------------------
__global__ void __launch_bounds__(256) scores_kernel(
    const float* __restrict__ enc, const float* __restrict__ u,
    float* __restrict__ logits, float2* __restrict__ partials) {
    const int b    = blockIdx.y;
    const int lane = threadIdx.x & 63;
    const int wv   = threadIdx.x >> 6;

    const float4* uv = (const float4*)(u + b * DD);
    const float4 u0 = uv[lane * 2 + 0];
    const float4 u1 = uv[lane * 2 + 1];

    const int rbase = blockIdx.x * 32 + wv * 8;   // this wave's 8 rows
    const float4* encb = (const float4*)(enc + (size_t)b * SS * DD);

    float rv[8];
    #pragma unroll
    for (int kk = 0; kk < 4; ++kk) {
        const int s0 = rbase + 2 * kk;            // adjacent pair: 4 KB contiguous
        const float4* r0 = encb + (size_t)s0 * (DD / 4);
        const float4* r1 = r0 + (DD / 4);
        float4 a0 = r0[lane * 2 + 0];
        float4 a1 = r0[lane * 2 + 1];
        float4 c0 = r1[lane * 2 + 0];
        float4 c1 = r1[lane * 2 + 1];
        float acc0 = a0.x * u0.x + a0.y * u0.y + a0.z * u0.z + a0.w * u0.w
                   + a1.x * u1.x + a1.y * u1.y + a1.z * u1.z + a1.w * u1.w;
        float acc1 = c0.x * u0.x + c0.y * u0.y + c0.z * u0.z + c0.w * u0.w
                   + c1.x * u1.x + c1.y * u1.y + c1.z * u1.z + c1.w * u1.w;
        #pragma unroll
        for (int off = 32; off > 0; off >>= 1) {
            acc0 += __shfl_xor(acc0, off, 64);
            acc1 += __shfl_xor(acc1, off, 64);
        }
        rv[2 * kk]     = acc0;                    // butterfly: all lanes hold sums
        rv[2 * kk + 1] = acc1;
        if (lane == 0)
            *(float2*)(logits + b * SS + s0) = make_float2(acc0, acc1);
    }

    // ---- per-block softmax partial: (max, sum exp) over its 32 rows --------
    float mw = rv[0];
    #pragma unroll
    for (int i = 1; i < 8; ++i) mw = fmaxf(mw, rv[i]);
    float sw = 0.f;
    #pragma unroll
    for (int i = 0; i < 8; ++i) sw += __expf(rv[i] - mw);

    __shared__ float2 wred[4];
    if (lane == 0) wred[wv] = make_float2(mw, sw);
    __syncthreads();
    if (threadIdx.x == 0) {
        float2 p0 = wred[0], p1 = wred[1], p2 = wred[2], p3 = wred[3];
        float mb = fmaxf(fmaxf(p0.x, p1.x), fmaxf(p2.x, p3.x));
        float sb = p0.y * __expf(p0.x - mb) + p1.y * __expf(p1.x - mb)
                 + p2.y * __expf(p2.x - mb) + p3.y * __expf(p3.x - mb);
        partials[b * SBLOCKS + blockIdx.x] = make_float2(mb, sb);
    }
}

// ---------------------------------------------------------------------------
// K3: normalize. grid = (2, B), block = 256; thread handles one float4.
// Every wave redundantly reduces the 64 (m,S) partials via shuffles (512 B,
// no LDS, no syncthreads), then applies exp(x-m)/S elementwise in place.
// ---------------------------------------------------------------------------
__global__ void __launch_bounds__(256) normalize_kernel(
    float* __restrict__ logits, const float2* __restrict__ partials) {
    const int b    = blockIdx.y;
    const int lane = threadIdx.x & 63;

    const float2 pl = partials[b * SBLOCKS + lane];
    float m = pl.x;
    #pragma unroll
    for (int off = 32; off > 0; off >>= 1)
        m = fmaxf(m, __shfl_xor(m, off, 64));
    float s = pl.y * __expf(pl.x - m);
    #pragma unroll
    for (int off = 32; off > 0; off >>= 1)
        s += __shfl_xor(s, off, 64);
    const float inv = 1.f / s;

    float4* p = (float4*)(logits + b * SS);
    const int idx = blockIdx.x * 256 + threadIdx.x;     // 512 float4s per batch
    float4 v = p[idx];
    v.x = __expf(v.x - m) * inv;
    v.y = __expf(v.y - m) * inv;
    v.z = __expf(v.z - m) * inv;
    v.w = __expf(v.w - m) * inv;
    p[idx] = v;
}

extern "C" void kernel_launch(void* const* d_in, const int* in_sizes, int n_in,
                              void* d_out, int out_size, void* d_ws, size_t ws_size,
                              hipStream_t stream) {
    const float* hidden = (const float*)d_in[0];   // [B,1,D]
    const float* enc    = (const float*)d_in[1];   // [B,S,D]
    const float* W      = (const float*)d_in[2];   // [D,D] (W[e,d])
    // d_in[3] = bias: per-batch constant on all logits -> softmax-invariant, unused.
    float* out  = (float*)d_out;                   // [B,1,S] fp32
    float* u    = (float*)d_ws;                    // B*D floats = 64 KB
    float2* partials = (float2*)((char*)d_ws + (size_t)BB * DD * sizeof(float));

    compute_u_kernel<<<dim3(DD / 64, BB), dim3(256), 0, stream>>>(hidden, W, u);
    scores_kernel<<<dim3(SBLOCKS, BB), dim3(256), 0, stream>>>(enc, u, out, partials);
    normalize_kernel<<<dim3(2, BB), dim3(256), 0, stream>>>(out, partials);
}